// Round 3
// baseline (311.543 us; speedup 1.0000x reference)
//
#include <hip/hip_runtime.h>
#include <hip/hip_bf16.h>

#define B_TOT 2048
#define N_CAP 200
#define D_DIM 256
#define NT    512
#define NW    8               // waves per block
#define CPW   25              // capsules per wave (200/8, exact)

__device__ __forceinline__ float bf_lo(unsigned u) { return __uint_as_float(u << 16); }
__device__ __forceinline__ float bf_hi(unsigned u) { return __uint_as_float(u & 0xffff0000u); }

__device__ __forceinline__ float wave_sum(float v) {
#pragma unroll
    for (int off = 32; off; off >>= 1) v += __shfl_xor(v, off);
    return v;
}

__global__ __launch_bounds__(NT, 4) void dyr_kernel(
        const float* __restrict__ embeds,
        const float* __restrict__ weights,
        float* __restrict__ out_v,
        float* __restrict__ out_c)
{
    __shared__ float s_part[NW][D_DIM];   // 8 KB
    __shared__ float red[NW];
    __shared__ float c_lds[N_CAP];

    const int b    = blockIdx.x;
    const int t    = threadIdx.x;
    const int wave = t >> 6;
    const int lane = t & 63;

    // ---- Load embeds ONCE, normalize per capsule, keep u_hat in REGISTERS ----
    // wave w, lane l holds capsule n = w + 8i, dims [4l, 4l+4), packed bf16.
    const float* eb = embeds + (size_t)b * (N_CAP * D_DIM) + lane * 4;

    uint2 u[CPW];   // 50 VGPRs
#pragma unroll
    for (int cc = 0; cc < 5; ++cc) {
        float4 xs[5];
#pragma unroll
        for (int j = 0; j < 5; ++j) {
            const int n = wave + (cc * 5 + j) * NW;
            xs[j] = *reinterpret_cast<const float4*>(eb + n * D_DIM);
        }
#pragma unroll
        for (int j = 0; j < 5; ++j) {
            const float4 x = xs[j];
            float ss = fmaf(x.x, x.x, fmaf(x.y, x.y, fmaf(x.z, x.z, x.w * x.w)));
            ss = wave_sum(ss);
            const float inv = 1.0f / fmaxf(sqrtf(ss), 1e-12f);
            union { __hip_bfloat16 h[4]; uint2 q; } pk;
            pk.h[0] = __float2bfloat16(x.x * inv);
            pk.h[1] = __float2bfloat16(x.y * inv);
            pk.h[2] = __float2bfloat16(x.z * inv);
            pk.h[3] = __float2bfloat16(x.w * inv);
            u[cc * 5 + j] = pk.q;
        }
    }

    // ---- logits as multiplicative state: e_i = exp(b_i), wave-uniform regs ----
    // (no max-subtraction needed: |b| <= ~7 over all iterations -> e in fp32 range)
    float e[CPW];
    {
        const float* wb = weights + (size_t)b * N_CAP + wave;
#pragma unroll
        for (int i = 0; i < CPW; ++i) e[i] = __expf(wb[8 * i]);
    }

    // ---- 3 routing iterations: 2 barriers each ----
    for (int r = 0; r < 3; ++r) {
        // exp-sum partial for softmax denominator
        float esp = 0.f;
#pragma unroll
        for (int i = 0; i < CPW; ++i) esp += e[i];
        if (lane == 0) red[wave] = esp;

        // einsum partial with UNSCALED weights (scale hoisted): acc = sum_i e_i * u_i
        float4 acc = make_float4(0.f, 0.f, 0.f, 0.f);
#pragma unroll
        for (int i = 0; i < CPW; ++i) {
            acc.x = fmaf(e[i], bf_lo(u[i].x), acc.x);
            acc.y = fmaf(e[i], bf_hi(u[i].x), acc.y);
            acc.z = fmaf(e[i], bf_lo(u[i].y), acc.z);
            acc.w = fmaf(e[i], bf_hi(u[i].y), acc.w);
        }
        __syncthreads();                       // B1: red[] visible

        float es = 0.f;
#pragma unroll
        for (int w = 0; w < NW; ++w) es += red[w];
        const float cs = (float)N_CAP / es;
        acc.x *= cs; acc.y *= cs; acc.z *= cs; acc.w *= cs;

        if (r == 2 && lane == 0) {             // stage c for coalesced output
#pragma unroll
            for (int i = 0; i < CPW; ++i) c_lds[wave + 8 * i] = e[i] * cs;
        }
        *reinterpret_cast<float4*>(&s_part[wave][lane * 4]) = acc;
        __syncthreads();                       // B2: s_part (and c_lds) visible

        // cross-wave reduce + squash, computed redundantly per wave
        float4 sd = make_float4(0.f, 0.f, 0.f, 0.f);
#pragma unroll
        for (int w = 0; w < NW; ++w) {
            const float4 p = *reinterpret_cast<const float4*>(&s_part[w][lane * 4]);
            sd.x += p.x; sd.y += p.y; sd.z += p.z; sd.w += p.w;
        }
        float ssn = fmaf(sd.x, sd.x, fmaf(sd.y, sd.y, fmaf(sd.z, sd.z, sd.w * sd.w)));
        ssn = wave_sum(ssn);
        const float scale = ssn / (1.0f + ssn) * rsqrtf(ssn + 1e-9f);
        const float4 vv = make_float4(scale * sd.x, scale * sd.y,
                                      scale * sd.z, scale * sd.w);

        if (r == 2) {
            if (wave == 0)
                *reinterpret_cast<float4*>(&out_v[(size_t)b * D_DIM + lane * 4]) = vv;
            if (t < N_CAP)
                out_c[(size_t)b * N_CAP + t] = c_lds[t];
        } else {
            // agreement: e_i *= exp(u_i . v)
#pragma unroll
            for (int i = 0; i < CPW; ++i) {
                float p = fmaf(bf_lo(u[i].x), vv.x,
                          fmaf(bf_hi(u[i].x), vv.y,
                          fmaf(bf_lo(u[i].y), vv.z,
                               bf_hi(u[i].y) * vv.w)));
                p = wave_sum(p);
                e[i] *= __expf(p);
            }
        }
    }
}

extern "C" void kernel_launch(void* const* d_in, const int* in_sizes, int n_in,
                              void* d_out, int out_size, void* d_ws, size_t ws_size,
                              hipStream_t stream) {
    const float* embeds  = (const float*)d_in[0];
    const float* weights = (const float*)d_in[1];
    float* out   = (float*)d_out;
    float* out_v = out;                                  // [2048, 256]
    float* out_c = out + (size_t)B_TOT * D_DIM;          // [2048, 200]

    dyr_kernel<<<B_TOT, NT, 0, stream>>>(embeds, weights, out_v, out_c);
}

// Round 4
// 295.552 us; speedup vs baseline: 1.0541x; 1.0541x over previous
//
#include <hip/hip_runtime.h>
#include <hip/hip_bf16.h>

#define B_TOT 2048
#define N_CAP 200
#define D_DIM 256
#define NT    512
#define NW    8               // waves per block
#define CPW   25              // capsules per wave (200/8, exact)

__device__ __forceinline__ float bf_lo(unsigned u) { return __uint_as_float(u << 16); }
__device__ __forceinline__ float bf_hi(unsigned u) { return __uint_as_float(u & 0xffff0000u); }

__device__ __forceinline__ float wave_sum(float v) {
#pragma unroll
    for (int off = 32; off; off >>= 1) v += __shfl_xor(v, off);
    return v;
}

// waves_per_eu(4,4): pin occupancy at 4 waves/EU so the allocator uses the
// full 128-VGPR budget instead of spilling u[]/e[] to scratch (R3: VGPR=64,
// 331 MB spill writes). 8-wave blocks -> 2 blocks/CU co-resident.
__global__ __launch_bounds__(NT) __attribute__((amdgpu_waves_per_eu(4, 4)))
void dyr_kernel(
        const float* __restrict__ embeds,
        const float* __restrict__ weights,
        float* __restrict__ out_v,
        float* __restrict__ out_c)
{
    __shared__ float s_part[NW][D_DIM];   // 8 KB
    __shared__ float red[NW];
    __shared__ float c_lds[N_CAP];

    const int b    = blockIdx.x;
    const int t    = threadIdx.x;
    const int wave = t >> 6;
    const int lane = t & 63;

    // ---- Load embeds ONCE, normalize per capsule, keep u_hat in REGISTERS ----
    // wave w, lane l holds capsule n = w + 8i, dims [4l, 4l+4), packed bf16.
    const float* eb = embeds + (size_t)b * (N_CAP * D_DIM) + lane * 4;

    uint2 u[CPW];   // 50 VGPRs
#pragma unroll
    for (int cc = 0; cc < 7; ++cc) {      // chunks of 4 capsules (25 = 6*4+1)
        const int base = cc * 4;
        const int cnt  = (cc == 6) ? 1 : 4;
        float4 xs[4];
#pragma unroll
        for (int j = 0; j < 4; ++j) {
            if (j < cnt) {
                const int n = wave + (base + j) * NW;
                xs[j] = *reinterpret_cast<const float4*>(eb + n * D_DIM);
            }
        }
#pragma unroll
        for (int j = 0; j < 4; ++j) {
            if (j < cnt) {
                const float4 x = xs[j];
                float ss = fmaf(x.x, x.x, fmaf(x.y, x.y, fmaf(x.z, x.z, x.w * x.w)));
                ss = wave_sum(ss);
                const float inv = 1.0f / fmaxf(sqrtf(ss), 1e-12f);
                union { __hip_bfloat16 h[4]; uint2 q; } pk;
                pk.h[0] = __float2bfloat16(x.x * inv);
                pk.h[1] = __float2bfloat16(x.y * inv);
                pk.h[2] = __float2bfloat16(x.z * inv);
                pk.h[3] = __float2bfloat16(x.w * inv);
                u[base + j] = pk.q;
            }
        }
    }

    // ---- logits as multiplicative state: e_i = exp(b_i), wave-uniform regs ----
    // (no max-subtraction needed: |b| <= ~8 over all iterations -> fp32 safe)
    float e[CPW];
    {
        const float* wb = weights + (size_t)b * N_CAP + wave;
#pragma unroll
        for (int i = 0; i < CPW; ++i) e[i] = __expf(wb[NW * i]);
    }

    // ---- 3 routing iterations: 2 barriers each ----
    for (int r = 0; r < 3; ++r) {
        // exp-sum partial for softmax denominator
        float esp = 0.f;
#pragma unroll
        for (int i = 0; i < CPW; ++i) esp += e[i];
        if (lane == 0) red[wave] = esp;

        // einsum partial with UNSCALED weights (scale hoisted): acc = sum_i e_i * u_i
        float4 acc = make_float4(0.f, 0.f, 0.f, 0.f);
#pragma unroll
        for (int i = 0; i < CPW; ++i) {
            acc.x = fmaf(e[i], bf_lo(u[i].x), acc.x);
            acc.y = fmaf(e[i], bf_hi(u[i].x), acc.y);
            acc.z = fmaf(e[i], bf_lo(u[i].y), acc.z);
            acc.w = fmaf(e[i], bf_hi(u[i].y), acc.w);
        }
        __syncthreads();                       // B1: red[] visible

        float es = 0.f;
#pragma unroll
        for (int w = 0; w < NW; ++w) es += red[w];
        const float cs = (float)N_CAP / es;
        acc.x *= cs; acc.y *= cs; acc.z *= cs; acc.w *= cs;

        if (r == 2 && lane == 0) {             // stage c for coalesced output
#pragma unroll
            for (int i = 0; i < CPW; ++i) c_lds[wave + NW * i] = e[i] * cs;
        }
        *reinterpret_cast<float4*>(&s_part[wave][lane * 4]) = acc;
        __syncthreads();                       // B2: s_part (and c_lds) visible

        // cross-wave reduce + squash, computed redundantly per wave
        float4 sd = make_float4(0.f, 0.f, 0.f, 0.f);
#pragma unroll
        for (int w = 0; w < NW; ++w) {
            const float4 p = *reinterpret_cast<const float4*>(&s_part[w][lane * 4]);
            sd.x += p.x; sd.y += p.y; sd.z += p.z; sd.w += p.w;
        }
        float ssn = fmaf(sd.x, sd.x, fmaf(sd.y, sd.y, fmaf(sd.z, sd.z, sd.w * sd.w)));
        ssn = wave_sum(ssn);
        const float scale = ssn / (1.0f + ssn) * rsqrtf(ssn + 1e-9f);
        const float4 vv = make_float4(scale * sd.x, scale * sd.y,
                                      scale * sd.z, scale * sd.w);

        if (r == 2) {
            if (wave == 0)
                *reinterpret_cast<float4*>(&out_v[(size_t)b * D_DIM + lane * 4]) = vv;
            if (t < N_CAP)
                out_c[(size_t)b * N_CAP + t] = c_lds[t];
        } else {
            // agreement: e_i *= exp(u_i . v)
#pragma unroll
            for (int i = 0; i < CPW; ++i) {
                float p = fmaf(bf_lo(u[i].x), vv.x,
                          fmaf(bf_hi(u[i].x), vv.y,
                          fmaf(bf_lo(u[i].y), vv.z,
                               bf_hi(u[i].y) * vv.w)));
                p = wave_sum(p);
                e[i] *= __expf(p);
            }
        }
    }
}

extern "C" void kernel_launch(void* const* d_in, const int* in_sizes, int n_in,
                              void* d_out, int out_size, void* d_ws, size_t ws_size,
                              hipStream_t stream) {
    const float* embeds  = (const float*)d_in[0];
    const float* weights = (const float*)d_in[1];
    float* out   = (float*)d_out;
    float* out_v = out;                                  // [2048, 256]
    float* out_c = out + (size_t)B_TOT * D_DIM;          // [2048, 200]

    dyr_kernel<<<B_TOT, NT, 0, stream>>>(embeds, weights, out_v, out_c);
}

// Round 5
// 252.005 us; speedup vs baseline: 1.2363x; 1.1728x over previous
//
#include <hip/hip_runtime.h>
#include <hip/hip_bf16.h>

#define B_TOT 2048
#define N_CAP 200
#define D_DIM 256
#define NT    512
#define NW    8               // waves per block
#define CPW   25              // capsules per wave (200/8, exact)

__device__ __forceinline__ float bf_lo(unsigned u) { return __uint_as_float(u << 16); }
__device__ __forceinline__ float bf_hi(unsigned u) { return __uint_as_float(u & 0xffff0000u); }

__device__ __forceinline__ float wave_sum(float v) {
#pragma unroll
    for (int off = 32; off; off >>= 1) v += __shfl_xor(v, off);
    return v;
}

// Register budget is the whole game here (R3/R4: 85 live regs vs the
// allocator's 64-VGPR point -> 257 MB of spill traffic). Persistent state is
// u[25] (50 VGPRs, per-lane bf16 fragments); the exp-logit state lives in LDS
// (wave-uniform, broadcast reads). Everything fits in 64 VGPRs -> no spill.
__global__ __launch_bounds__(NT, 4)
void dyr_kernel(
        const float* __restrict__ embeds,
        const float* __restrict__ weights,
        float* __restrict__ out_v,
        float* __restrict__ out_c)
{
    __shared__ float s_part[NW][D_DIM];   // 8 KB
    __shared__ float red[NW];
    __shared__ float e_lds[N_CAP];        // e_i = exp(b_i); wave w owns [w + 8i]

    const int b    = blockIdx.x;
    const int t    = threadIdx.x;
    const int wave = t >> 6;
    const int lane = t & 63;

    // ---- init exp-logit state (owner-wave writes; read only by owner until
    //      the r==2 out_c pass, which is barrier-separated) ----
    if (lane < CPW)
        e_lds[wave + NW * lane] = __expf(weights[(size_t)b * N_CAP + wave + NW * lane]);

    // ---- Load embeds ONCE, normalize per capsule, keep u_hat in REGISTERS ----
    // wave w, lane l holds capsule n = w + 8i, dims [4l, 4l+4), packed bf16.
    const float* eb = embeds + (size_t)b * (N_CAP * D_DIM) + lane * 4;

    uint2 u[CPW];   // 50 VGPRs
#pragma unroll
    for (int cc = 0; cc < 5; ++cc) {      // 5 chunks of 5: bounded in-flight float4s
        float4 xs[5];
#pragma unroll
        for (int j = 0; j < 5; ++j) {
            const int n = wave + (cc * 5 + j) * NW;
            xs[j] = *reinterpret_cast<const float4*>(eb + n * D_DIM);
        }
#pragma unroll
        for (int j = 0; j < 5; ++j) {
            const float4 x = xs[j];
            float ss = fmaf(x.x, x.x, fmaf(x.y, x.y, fmaf(x.z, x.z, x.w * x.w)));
            ss = wave_sum(ss);
            const float inv = 1.0f / fmaxf(sqrtf(ss), 1e-12f);
            union { __hip_bfloat16 h[4]; uint2 q; } pk;
            pk.h[0] = __float2bfloat16(x.x * inv);
            pk.h[1] = __float2bfloat16(x.y * inv);
            pk.h[2] = __float2bfloat16(x.z * inv);
            pk.h[3] = __float2bfloat16(x.w * inv);
            u[cc * 5 + j] = pk.q;
        }
    }

    // ---- iteration-0 einsum: acc = sum_i e_i*u_i, esp = sum_i e_i ----
    float esp = 0.f;
    float4 acc = make_float4(0.f, 0.f, 0.f, 0.f);
#pragma unroll
    for (int i = 0; i < CPW; ++i) {
        const float ei = e_lds[wave + NW * i];   // wave-uniform broadcast
        esp += ei;
        acc.x = fmaf(ei, bf_lo(u[i].x), acc.x);
        acc.y = fmaf(ei, bf_hi(u[i].x), acc.y);
        acc.z = fmaf(ei, bf_lo(u[i].y), acc.z);
        acc.w = fmaf(ei, bf_hi(u[i].y), acc.w);
    }

    // ---- 3 routing iterations: 2 barriers each ----
    for (int r = 0; r < 3; ++r) {
        if (lane == 0) red[wave] = esp;
        __syncthreads();                       // B1: red[] visible

        float es = 0.f;
#pragma unroll
        for (int w = 0; w < NW; ++w) es += red[w];
        const float cs = (float)N_CAP / es;
        acc.x *= cs; acc.y *= cs; acc.z *= cs; acc.w *= cs;
        *reinterpret_cast<float4*>(&s_part[wave][lane * 4]) = acc;

        if (r == 2 && t < N_CAP)               // c = e * N/es, coalesced
            out_c[(size_t)b * N_CAP + t] = e_lds[t] * cs;
        __syncthreads();                       // B2: s_part visible

        // cross-wave reduce + squash, computed redundantly per wave
        float4 sd = make_float4(0.f, 0.f, 0.f, 0.f);
#pragma unroll
        for (int w = 0; w < NW; ++w) {
            const float4 p = *reinterpret_cast<const float4*>(&s_part[w][lane * 4]);
            sd.x += p.x; sd.y += p.y; sd.z += p.z; sd.w += p.w;
        }
        float ssn = fmaf(sd.x, sd.x, fmaf(sd.y, sd.y, fmaf(sd.z, sd.z, sd.w * sd.w)));
        ssn = wave_sum(ssn);
        const float scale = ssn / (1.0f + ssn) * rsqrtf(ssn + 1e-9f);
        const float4 vv = make_float4(scale * sd.x, scale * sd.y,
                                      scale * sd.z, scale * sd.w);

        if (r == 2) {
            if (wave == 0)
                *reinterpret_cast<float4*>(&out_v[(size_t)b * D_DIM + lane * 4]) = vv;
        } else {
            // fused agreement + next-iteration einsum (single pass over u):
            // e'_i = e_i * exp(u_i . v);  esp += e'_i;  acc += e'_i * u_i
            esp = 0.f;
            acc = make_float4(0.f, 0.f, 0.f, 0.f);
#pragma unroll
            for (int i = 0; i < CPW; ++i) {
                float p = fmaf(bf_lo(u[i].x), vv.x,
                          fmaf(bf_hi(u[i].x), vv.y,
                          fmaf(bf_lo(u[i].y), vv.z,
                               bf_hi(u[i].y) * vv.w)));
                p = wave_sum(p);                       // wave-uniform
                const float en = e_lds[wave + NW * i] * __expf(p);
                if (lane == 0) e_lds[wave + NW * i] = en;
                esp += en;
                acc.x = fmaf(en, bf_lo(u[i].x), acc.x);
                acc.y = fmaf(en, bf_hi(u[i].x), acc.y);
                acc.z = fmaf(en, bf_lo(u[i].y), acc.z);
                acc.w = fmaf(en, bf_hi(u[i].y), acc.w);
            }
        }
    }
}

extern "C" void kernel_launch(void* const* d_in, const int* in_sizes, int n_in,
                              void* d_out, int out_size, void* d_ws, size_t ws_size,
                              hipStream_t stream) {
    const float* embeds  = (const float*)d_in[0];
    const float* weights = (const float*)d_in[1];
    float* out   = (float*)d_out;
    float* out_v = out;                                  // [2048, 256]
    float* out_c = out + (size_t)B_TOT * D_DIM;          // [2048, 200]

    dyr_kernel<<<B_TOT, NT, 0, stream>>>(embeds, weights, out_v, out_c);
}

// Round 6
// 206.666 us; speedup vs baseline: 1.5075x; 1.2194x over previous
//
#include <hip/hip_runtime.h>
#include <hip/hip_bf16.h>

#define B_TOT 2048
#define N_CAP 200
#define D_DIM 256
#define NT    640
#define NW    10              // waves per block
#define CPW   20              // capsules per wave (200/10, exact)

__device__ __forceinline__ float bf_lo(unsigned u) { return __uint_as_float(u << 16); }
__device__ __forceinline__ float bf_hi(unsigned u) { return __uint_as_float(u & 0xffff0000u); }

__device__ __forceinline__ float wave_sum(float v) {
#pragma unroll
    for (int off = 32; off; off >>= 1) v += __shfl_xor(v, off);
    return v;
}

// Register budget is the whole game (R3-R5: allocator insists on the 64-VGPR
// point; any peak above it spills u[] to scratch -> 175-331 MB of HBM spill
// traffic). Design to FIT 64: 10 waves x 20 capsules -> u[20] = 40 VGPRs
// persistent; load pipeline bounded to 2 in-flight float4s via sched_barrier.
__global__ __launch_bounds__(NT)
void dyr_kernel(
        const float* __restrict__ embeds,
        const float* __restrict__ weights,
        float* __restrict__ out_v,
        float* __restrict__ out_c)
{
    __shared__ float s_part[NW][D_DIM];   // 10 KB
    __shared__ float red[NW];
    __shared__ float e_lds[N_CAP];        // e_i = exp(b_i); wave w owns [w + 10i]

    const int b    = blockIdx.x;
    const int t    = threadIdx.x;
    const int wave = t >> 6;
    const int lane = t & 63;

    // ---- init exp-logit state (owner-wave lanes write; later reads are
    //      same-wave broadcasts, ordered by lgkmcnt; cross-wave reads only
    //      after barriers) ----
    if (lane < CPW)
        e_lds[wave + NW * lane] = __expf(weights[(size_t)b * N_CAP + wave + NW * lane]);

    // ---- Load embeds ONCE, normalize per capsule, keep u_hat in REGISTERS.
    // wave w, lane l holds capsule n = w + 10i, dims [4l, 4l+4), packed bf16.
    // Depth-2 pipeline; sched_barrier stops the compiler from hoisting all 20
    // loads (that hoist is what spilled R2-R5). ----
    const float* eb = embeds + (size_t)b * (N_CAP * D_DIM) + lane * 4;

    uint2 u[CPW];   // 40 VGPRs
    float4 xc = *reinterpret_cast<const float4*>(eb + wave * D_DIM);
#pragma unroll
    for (int i = 0; i < CPW; ++i) {
        float4 xn;
        if (i + 1 < CPW)
            xn = *reinterpret_cast<const float4*>(eb + (wave + (i + 1) * NW) * D_DIM);
        float ss = fmaf(xc.x, xc.x, fmaf(xc.y, xc.y, fmaf(xc.z, xc.z, xc.w * xc.w)));
        ss = wave_sum(ss);
        const float inv = 1.0f / fmaxf(sqrtf(ss), 1e-12f);
        union { __hip_bfloat16 h[4]; uint2 q; } pk;
        pk.h[0] = __float2bfloat16(xc.x * inv);
        pk.h[1] = __float2bfloat16(xc.y * inv);
        pk.h[2] = __float2bfloat16(xc.z * inv);
        pk.h[3] = __float2bfloat16(xc.w * inv);
        u[i] = pk.q;
        __builtin_amdgcn_sched_barrier(0);   // no cross-capsule code motion
        if (i + 1 < CPW) xc = xn;
    }

    // ---- iteration-0 einsum: acc = sum_i e_i*u_i, esp = sum_i e_i ----
    float esp = 0.f;
    float4 acc = make_float4(0.f, 0.f, 0.f, 0.f);
#pragma unroll
    for (int i = 0; i < CPW; ++i) {
        const float ei = e_lds[wave + NW * i];   // wave-uniform broadcast
        esp += ei;
        acc.x = fmaf(ei, bf_lo(u[i].x), acc.x);
        acc.y = fmaf(ei, bf_hi(u[i].x), acc.y);
        acc.z = fmaf(ei, bf_lo(u[i].y), acc.z);
        acc.w = fmaf(ei, bf_hi(u[i].y), acc.w);
    }

    // ---- 3 routing iterations: 2 barriers each ----
    for (int r = 0; r < 3; ++r) {
        if (lane == 0) red[wave] = esp;
        __syncthreads();                       // B1: red[] (and final e_lds) visible

        float es = 0.f;
#pragma unroll
        for (int w = 0; w < NW; ++w) es += red[w];
        const float cs = (float)N_CAP / es;
        acc.x *= cs; acc.y *= cs; acc.z *= cs; acc.w *= cs;
        *reinterpret_cast<float4*>(&s_part[wave][lane * 4]) = acc;

        if (r == 2 && t < N_CAP)               // c = e * N/es, coalesced
            out_c[(size_t)b * N_CAP + t] = e_lds[t] * cs;
        __syncthreads();                       // B2: s_part visible

        // cross-wave reduce + squash, computed redundantly per wave
        float4 sd = make_float4(0.f, 0.f, 0.f, 0.f);
#pragma unroll
        for (int w = 0; w < NW; ++w) {
            const float4 p = *reinterpret_cast<const float4*>(&s_part[w][lane * 4]);
            sd.x += p.x; sd.y += p.y; sd.z += p.z; sd.w += p.w;
        }
        float ssn = fmaf(sd.x, sd.x, fmaf(sd.y, sd.y, fmaf(sd.z, sd.z, sd.w * sd.w)));
        ssn = wave_sum(ssn);
        const float scale = ssn / (1.0f + ssn) * rsqrtf(ssn + 1e-9f);
        const float4 vv = make_float4(scale * sd.x, scale * sd.y,
                                      scale * sd.z, scale * sd.w);

        if (r == 2) {
            if (wave == 0)
                *reinterpret_cast<float4*>(&out_v[(size_t)b * D_DIM + lane * 4]) = vv;
        } else {
            // fused agreement + next-iteration einsum (single pass over u):
            // e'_i = e_i * exp(u_i . v);  esp += e'_i;  acc += e'_i * u_i
            esp = 0.f;
            acc = make_float4(0.f, 0.f, 0.f, 0.f);
#pragma unroll
            for (int i = 0; i < CPW; ++i) {
                float p = fmaf(bf_lo(u[i].x), vv.x,
                          fmaf(bf_hi(u[i].x), vv.y,
                          fmaf(bf_lo(u[i].y), vv.z,
                               bf_hi(u[i].y) * vv.w)));
                p = wave_sum(p);                       // wave-uniform
                const float en = e_lds[wave + NW * i] * __expf(p);
                if (lane == 0) e_lds[wave + NW * i] = en;
                esp += en;
                acc.x = fmaf(en, bf_lo(u[i].x), acc.x);
                acc.y = fmaf(en, bf_hi(u[i].x), acc.y);
                acc.z = fmaf(en, bf_lo(u[i].y), acc.z);
                acc.w = fmaf(en, bf_hi(u[i].y), acc.w);
            }
        }
    }
}

extern "C" void kernel_launch(void* const* d_in, const int* in_sizes, int n_in,
                              void* d_out, int out_size, void* d_ws, size_t ws_size,
                              hipStream_t stream) {
    const float* embeds  = (const float*)d_in[0];
    const float* weights = (const float*)d_in[1];
    float* out   = (float*)d_out;
    float* out_v = out;                                  // [2048, 256]
    float* out_c = out + (size_t)B_TOT * D_DIM;          // [2048, 200]

    dyr_kernel<<<B_TOT, NT, 0, stream>>>(embeds, weights, out_v, out_c);
}